// Round 7
// baseline (202.285 us; speedup 1.0000x reference)
//
#include <hip/hip_runtime.h>

// RepulsionXTB: per-pair repulsion energy, segment-summed per molecule.
//
// Inputs (setup_inputs order, harness converts ints to int32):
//   d_in[0] element_idxs  int32  [M*A]   (M=2048, A=64 -> 131072)
//   d_in[1] neighbor_idxs int32  [2*P]   (P=8388608)
//   d_in[2] distances     f32    [P]
//   d_in[3] y_ab          f32    [16]   == outer(y_eff, y_eff)       (separable)
//   d_in[4] sqrt_alpha_ab f32    [16]   == sqrt(outer(alpha, alpha)) (separable)
//   d_in[5] k_rep_ab      f32    [16]   (1.5 everywhere except [0,0]=1.0)
// Output: energies f32 [M]
//
// R7: cp.async-style restructure. R1-R6 all land 50-66us with every pipe
// <25% busy -> per-iteration waitcnt drain serializes waves. Fix: DMA the
// pair stream into LDS via global_load_lds (16B), double-buffered, with
// RAW s_barrier + manual s_waitcnt vmcnt(1) so next chunk's DMA stays in
// flight across the barrier (__syncthreads would drain vmcnt(0)).
// One drain point per 1024 pairs instead of per 4.

#define AB_D 1.8897261258369282
#define L2E  1.4426950408889634f   // log2(e)

typedef unsigned int u32;

// ---------------- kernel 1: pack species to 2 bits/atom + zero output -------
__global__ __launch_bounds__(256) void pack_zero_kernel(
    const int* __restrict__ elem, int natoms, int nwords,
    u32* __restrict__ packed, float* __restrict__ out, int M)
{
    int g = blockIdx.x * blockDim.x + threadIdx.x;
    if (g < M) out[g] = 0.0f;
    if (g < nwords) {
        int base = g * 16;
        u32 w = 0u;
        if (base + 16 <= natoms) {
            const int4* p = (const int4*)(elem + base);
            #pragma unroll
            for (int q = 0; q < 4; ++q) {
                int4 v = p[q];
                w |= ((u32)v.x & 3u) << (2 * (4 * q + 0));
                w |= ((u32)v.y & 3u) << (2 * (4 * q + 1));
                w |= ((u32)v.z & 3u) << (2 * (4 * q + 2));
                w |= ((u32)v.w & 3u) << (2 * (4 * q + 3));
            }
        } else {
            for (int j = 0; j < 16; ++j) {
                int a = base + j;
                u32 s = (a < natoms) ? ((u32)elem[a] & 3u) : 0u;
                w |= s << (2 * j);
            }
        }
        packed[g] = w;
    }
}

// 4-way select by 2-bit index, pure VALU (3 cndmask)
__device__ __forceinline__ float sel4(u32 s, float a, float b, float c, float d)
{
    float lo = (s & 1u) ? b : a;
    float hi = (s & 1u) ? d : c;
    return (s & 2u) ? hi : lo;
}

// async 16B/lane global->LDS DMA; lds base must be wave-uniform (HW adds lane*16)
__device__ __forceinline__ void async_load16(const void* g, void* lds_base)
{
    __builtin_amdgcn_global_load_lds(
        (const __attribute__((address_space(1))) u32*)g,
        (__attribute__((address_space(3))) u32*)lds_base,
        16, 0, 0);
}

// ---------------- kernel 2 (fast path): pipelined pair loop -----------------
// LDS: [acc 8KB][pk 32KB][stage 2 x 12KB] = 64KB; 1024 thr, 2 blocks/CU.
// chunk = 256 quads = 1024 pairs = 12KB (nb0 4KB | nb1 4KB | dist 4KB).
__global__ __launch_bounds__(1024, 8) void rep_pipe_kernel(
    const int* __restrict__ nbr, const float* __restrict__ dist,
    const u32* __restrict__ packed_g,
    const float* __restrict__ y_ab, const float* __restrict__ sa_ab,
    long long P, int M, int nwords, int ashift,
    int chunks_per_block, long long total_chunks,
    float* __restrict__ partials)
{
    __shared__ char smem[65536];
    float* acc   = (float*)smem;            // [0, 8192)
    u32*   pk    = (u32*)(smem + 8192);     // [8192, 40960)
    char*  stage = smem + 40960;            // 2 x 12288

    const int tid  = threadIdx.x;
    const int wave = tid >> 6;
    const int lane = tid & 63;

    for (int m = tid; m < M; m += 1024) acc[m] = 0.0f;
    for (int w = tid; w < nwords; w += 1024) pk[w] = packed_g[w];

    const float yv0 = sqrtf(y_ab[0]),  yv1 = sqrtf(y_ab[5]);
    const float yv2 = sqrtf(y_ab[10]), yv3 = sqrtf(y_ab[15]);
    const float sL2E = sqrtf(L2E);
    const float av0 = sqrtf(sa_ab[0])  * sL2E, av1 = sqrtf(sa_ab[5])  * sL2E;
    const float av2 = sqrtf(sa_ab[10]) * sL2E, av3 = sqrtf(sa_ab[15]) * sL2E;
    __syncthreads();   // full drain once, before the pipeline starts

    const float ABf   = (float)AB_D;
    const float DMIN  = (float)(1e-7 * AB_D);
    const float RC    = (float)(5.2 * AB_D);
    const float RCINV = (float)(1.0 / (5.2 * AB_D));

    const char* g_nb0  = (const char*)nbr;
    const char* g_nb1  = (const char*)(nbr + P);
    const char* g_dist = (const char*)dist;

    const long long c0 = (long long)blockIdx.x * chunks_per_block;

    // waves 0-11: wave w copies stream (w>>2), segment (w&3) -> one 1KB DMA
    auto stage_load = [&](int buf, long long c) {
        if (wave < 12 && c < total_chunks) {
            int stream = wave >> 2, seg = wave & 3;
            const char* gb = (stream == 0) ? g_nb0 : (stream == 1) ? g_nb1 : g_dist;
            const char* gp = gb + (c << 12) + (seg << 10) + ((long long)lane << 4);
            char* lp = stage + buf * 12288 + stream * 4096 + seg * 1024;
            async_load16(gp, lp);
        }
    };

    auto process_chunk = [&](int buf, long long c) {
        if (c >= total_chunks) return;
        const u32*   b0 = (const u32*)(stage + buf * 12288);
        const u32*   b1 = (const u32*)(stage + buf * 12288 + 4096);
        const float* bd = (const float*)(stage + buf * 12288 + 8192);
        u32   ua0  = b0[tid];          // stride-1 ds_read_b32: conflict-free
        u32   ua1  = b1[tid];
        float draw = bd[tid];
        float d = fmaxf(draw * ABf, DMIN);
        if (d < RC) {                  // early-out: culled pairs do no LDS ops
            u32 s0 = (pk[ua0 >> 4] >> ((ua0 & 15u) * 2u)) & 3u;
            u32 s1 = (pk[ua1 >> 4] >> ((ua1 & 15u) * 2u)) & 3u;
            float y  = sel4(s0, yv0, yv1, yv2, yv3) * sel4(s1, yv0, yv1, yv2, yv3);
            float sa = sel4(s0, av0, av1, av2, av3) * sel4(s1, av0, av1, av2, av3);
            float sq   = __builtin_amdgcn_sqrtf(d);
            float fac  = ((s0 | s1) == 0u) ? 1.0f : sq;   // H-H: kr=1, else 1.5
            float drep = d * fac;
            float x    = d * RCINV;
            float om   = fmaf(-x, x, 1.0f);
            float r    = __builtin_amdgcn_rcpf(om);
            float e    = fmaf(-L2E, r, L2E);
            float arg  = fmaf(-sa, drep, e);
            float rep  = y * __builtin_amdgcn_rcpf(d) * __builtin_amdgcn_exp2f(arg);
            atomicAdd(&acc[ua0 >> ashift], rep);
        }
    };

    // pipeline: per wave, 1 outstanding DMA; wait vmcnt(1) keeps next chunk
    // in flight across the RAW barrier (no __syncthreads drain).
    stage_load(0, c0);
    const int nc = chunks_per_block;
    for (int i = 0; i + 1 < nc; ++i) {
        stage_load((i + 1) & 1, c0 + i + 1);
        asm volatile("s_waitcnt vmcnt(1)" ::: "memory");
        __builtin_amdgcn_s_barrier();          // chunk i fully in LDS
        process_chunk(i & 1, c0 + i);
        __builtin_amdgcn_s_barrier();          // all readers of buf done
    }
    asm volatile("s_waitcnt vmcnt(0)" ::: "memory");
    __builtin_amdgcn_s_barrier();
    process_chunk((nc - 1) & 1, c0 + nc - 1);

    __syncthreads();
    float* row = partials + (size_t)blockIdx.x * (size_t)M;
    for (int m = tid; m < M; m += 1024) row[m] = acc[m];
}

// ---------------- kernel 2 (fallback, R6 structure) -------------------------
__global__ __launch_bounds__(1024, 8) void rep_fallback_kernel(
    const int* __restrict__ nbr, const float* __restrict__ dist,
    const u32* __restrict__ packed_g,
    const float* __restrict__ y_ab, const float* __restrict__ sa_ab,
    long long P, int M, int nwords, int ashift, int A,
    float* __restrict__ out)
{
    extern __shared__ char smem[];
    float* acc = (float*)smem;
    u32*   pk  = (u32*)(smem + (size_t)M * 4);

    const int tid = threadIdx.x, nthr = blockDim.x;
    for (int m = tid; m < M; m += nthr) acc[m] = 0.0f;
    for (int w = tid; w < nwords; w += nthr) pk[w] = packed_g[w];
    const float yv0 = sqrtf(y_ab[0]),  yv1 = sqrtf(y_ab[5]);
    const float yv2 = sqrtf(y_ab[10]), yv3 = sqrtf(y_ab[15]);
    const float sL2E = sqrtf(L2E);
    const float av0 = sqrtf(sa_ab[0])  * sL2E, av1 = sqrtf(sa_ab[5])  * sL2E;
    const float av2 = sqrtf(sa_ab[10]) * sL2E, av3 = sqrtf(sa_ab[15]) * sL2E;
    __syncthreads();

    const float ABf   = (float)AB_D;
    const float DMIN  = (float)(1e-7 * AB_D);
    const float RC    = (float)(5.2 * AB_D);
    const float RCINV = (float)(1.0 / (5.2 * AB_D));

    auto process = [&](u32 ua0, u32 ua1, float draw) {
        float d = fmaxf(draw * ABf, DMIN);
        if (d < RC) {
            u32 s0 = (pk[ua0 >> 4] >> ((ua0 & 15u) * 2u)) & 3u;
            u32 s1 = (pk[ua1 >> 4] >> ((ua1 & 15u) * 2u)) & 3u;
            float y  = sel4(s0, yv0, yv1, yv2, yv3) * sel4(s1, yv0, yv1, yv2, yv3);
            float sa = sel4(s0, av0, av1, av2, av3) * sel4(s1, av0, av1, av2, av3);
            float sq   = __builtin_amdgcn_sqrtf(d);
            float fac  = ((s0 | s1) == 0u) ? 1.0f : sq;
            float drep = d * fac;
            float x    = d * RCINV;
            float om   = fmaf(-x, x, 1.0f);
            float r    = __builtin_amdgcn_rcpf(om);
            float e    = fmaf(-L2E, r, L2E);
            float arg  = fmaf(-sa, drep, e);
            float rep  = y * __builtin_amdgcn_rcpf(d) * __builtin_amdgcn_exp2f(arg);
            u32 mol = (ashift >= 0) ? (ua0 >> ashift) : (ua0 / (u32)A);
            atomicAdd(&acc[mol], rep);
        }
    };

    long long P4 = P >> 2;
    long long gstride = (long long)gridDim.x * nthr;
    const int* nb0 = nbr;
    const int* nb1 = nbr + P;
    for (long long q = (long long)blockIdx.x * nthr + tid; q < P4; q += gstride) {
        int4   i0 = ((const int4*)nb0)[q];
        int4   i1 = ((const int4*)nb1)[q];
        float4 dv = ((const float4*)dist)[q];
        process((u32)i0.x, (u32)i1.x, dv.x);
        process((u32)i0.y, (u32)i1.y, dv.y);
        process((u32)i0.z, (u32)i1.z, dv.z);
        process((u32)i0.w, (u32)i1.w, dv.w);
    }
    if (blockIdx.x == 0) {
        for (long long p = (P4 << 2) + tid; p < P; p += nthr)
            process((u32)nb0[p], (u32)nb1[p], dist[p]);
    }
    __syncthreads();
    for (int m = tid; m < M; m += nthr) {
        float v = acc[m];
        if (v != 0.0f) atomicAdd(&out[m], v);
    }
}

// ---------------- kernel 3: column-sum the partial rows ---------------------
__global__ __launch_bounds__(256) void reduce_kernel(
    const float* __restrict__ partials, float* __restrict__ out,
    int M, int nblk, int rows_per)
{
    int m = blockIdx.x * blockDim.x + threadIdx.x;
    if (m >= M) return;
    int r0 = blockIdx.y * rows_per;
    int r1 = r0 + rows_per;
    if (r1 > nblk) r1 = nblk;
    if (r0 >= r1) return;
    float s0 = 0.f, s1 = 0.f, s2 = 0.f, s3 = 0.f;
    int r = r0;
    for (; r + 3 < r1; r += 4) {
        s0 += partials[(size_t)(r + 0) * M + m];
        s1 += partials[(size_t)(r + 1) * M + m];
        s2 += partials[(size_t)(r + 2) * M + m];
        s3 += partials[(size_t)(r + 3) * M + m];
    }
    for (; r < r1; ++r) s0 += partials[(size_t)r * M + m];
    atomicAdd(&out[m], (s0 + s1) + (s2 + s3));
}

extern "C" void kernel_launch(void* const* d_in, const int* in_sizes, int n_in,
                              void* d_out, int out_size, void* d_ws, size_t ws_size,
                              hipStream_t stream)
{
    const int*   elem  = (const int*)d_in[0];
    const int*   nbr   = (const int*)d_in[1];
    const float* dist  = (const float*)d_in[2];
    const float* y_ab  = (const float*)d_in[3];
    const float* sa_ab = (const float*)d_in[4];
    float* out = (float*)d_out;

    const int natoms = in_sizes[0];
    const long long P = (long long)in_sizes[2];
    const int M = out_size;
    const int A = (M > 0) ? natoms / M : 1;
    int ashift = -1;
    if (A > 0 && (A & (A - 1)) == 0) {
        int s = 0;
        while ((1 << s) < A) ++s;
        ashift = s;
    }
    const int nwords = (natoms + 15) / 16;

    // workspace: [packed (256B aligned)][partials: 512*M f32]
    size_t packed_bytes = ((size_t)nwords * 4 + 255) & ~(size_t)255;
    if (ws_size < (size_t)nwords * 4) return;
    u32* packed = (u32*)d_ws;

    const int NBLK = 512;
    bool have_partials = (ws_size >= packed_bytes + (size_t)NBLK * M * 4);
    float* partials = have_partials ? (float*)((char*)d_ws + packed_bytes) : nullptr;

    bool fast = have_partials && (ashift >= 0) && (M >= 1) && (M <= 2048) &&
                (nwords <= 8192) && (P > 0) && (P % 1024 == 0);

    // kernel 1: pack + zero out
    {
        int total = (nwords > M) ? nwords : M;
        int g = (total + 255) / 256;
        hipLaunchKernelGGL(pack_zero_kernel, dim3(g), dim3(256), 0, stream,
                           elem, natoms, nwords, packed, out, M);
    }

    if (fast) {
        long long total_chunks = P / 1024;                  // 256 quads/chunk
        int cpb = (int)((total_chunks + NBLK - 1) / NBLK);
        hipLaunchKernelGGL(rep_pipe_kernel, dim3(NBLK), dim3(1024), 0, stream,
                           nbr, dist, packed, y_ab, sa_ab,
                           P, M, nwords, ashift, cpb, total_chunks, partials);
        const int SPLIT = 32;
        int rows_per = (NBLK + SPLIT - 1) / SPLIT;
        dim3 grid((M + 255) / 256, SPLIT);
        hipLaunchKernelGGL(reduce_kernel, grid, dim3(256), 0, stream,
                           partials, out, M, NBLK, rows_per);
    } else {
        size_t smem = (size_t)M * 4 + (size_t)nwords * 4;
        hipLaunchKernelGGL(rep_fallback_kernel, dim3(NBLK), dim3(1024), smem, stream,
                           nbr, dist, packed, y_ab, sa_ab,
                           P, M, nwords, ashift, A, out);
    }
}